// Round 8
// baseline (276.063 us; speedup 1.0000x reference)
//
#include <hip/hip_runtime.h>
#include <math.h>

#define D_MODEL 1024
#define SEQ     1024
#define BATCH   4
#define NTOK    (BATCH * SEQ)   // 4096

typedef __bf16 bf16;
using bfrag = __attribute__((ext_vector_type(8))) __bf16;
using ffrag = __attribute__((ext_vector_type(4))) float;

__device__ __forceinline__ ffrag mfma16(bfrag a, bfrag b, ffrag c) {
  return __builtin_amdgcn_mfma_f32_16x16x32_bf16(a, b, c, 0, 0, 0);
}

__device__ __forceinline__ void gload_lds16(const void* g, void* l) {
  __builtin_amdgcn_global_load_lds(
      (const __attribute__((address_space(1))) void*)g,
      (__attribute__((address_space(3))) void*)l, 16, 0, 0);
}

// ---------------------------------------------------------------- all weights fp32 -> bf16 (one launch)
__global__ void convert_all(const float* __restrict__ s0, bf16* __restrict__ d0, int n0,
                            const float* __restrict__ s1, bf16* __restrict__ d1, int n1,
                            const float* __restrict__ s2, bf16* __restrict__ d2, int n2,
                            const float* __restrict__ s3, bf16* __restrict__ d3, int n3,
                            float scale, int limit0) {
  const float* src; bf16* dst; int n; int limit = 0;
  switch (blockIdx.y) {
    case 0: src = s0; dst = d0; n = n0; limit = limit0; break;
    case 1: src = s1; dst = d1; n = n1; break;
    case 2: src = s2; dst = d2; n = n2; break;
    default: src = s3; dst = d3; n = n3; break;
  }
  int i = blockIdx.x * blockDim.x + threadIdx.x;
  const int stride = gridDim.x * blockDim.x;
  for (; i < n; i += stride) {
    float4 v = ((const float4*)src)[i];
    float sc = (i < limit) ? scale : 1.0f;
    bf16* d = dst + (size_t)i * 4;
    d[0] = (bf16)(v.x * sc); d[1] = (bf16)(v.y * sc);
    d[2] = (bf16)(v.z * sc); d[3] = (bf16)(v.w * sc);
  }
}

__global__ void scale_bias(const float* __restrict__ src, float* __restrict__ dst,
                           int n, int limit, float scale) {
  int i = blockIdx.x * blockDim.x + threadIdx.x;
  if (i < n) dst[i] = src[i] * (i < limit ? scale : 1.0f);
}

// ---------------------------------------------------------------- LayerNorm (fp32 in, bf16 out)
__global__ __launch_bounds__(256) void ln_row(const float* __restrict__ x,
                                              const float* __restrict__ gamma,
                                              const float* __restrict__ beta,
                                              bf16* __restrict__ out) {
  const int row = blockIdx.x, tid = threadIdx.x;
  const float4 v = ((const float4*)(x + (size_t)row * D_MODEL))[tid];
  float s  = v.x + v.y + v.z + v.w;
  float ss = v.x * v.x + v.y * v.y + v.z * v.z + v.w * v.w;
#pragma unroll
  for (int off = 32; off >= 1; off >>= 1) {
    s  += __shfl_xor(s, off);
    ss += __shfl_xor(ss, off);
  }
  __shared__ float rs[4], rss[4];
  const int w = tid >> 6;
  if ((tid & 63) == 0) { rs[w] = s; rss[w] = ss; }
  __syncthreads();
  s  = rs[0] + rs[1] + rs[2] + rs[3];
  ss = rss[0] + rss[1] + rss[2] + rss[3];
  const float mu   = s * (1.0f / D_MODEL);
  const float var  = ss * (1.0f / D_MODEL) - mu * mu;
  const float rstd = rsqrtf(var + 1e-5f);
  const float4 gv = ((const float4*)gamma)[tid];
  const float4 bv = ((const float4*)beta)[tid];
  bf16* o = out + (size_t)row * D_MODEL + tid * 4;
  o[0] = (bf16)((v.x - mu) * rstd * gv.x + bv.x);
  o[1] = (bf16)((v.y - mu) * rstd * gv.y + bv.y);
  o[2] = (bf16)((v.z - mu) * rstd * gv.z + bv.z);
  o[3] = (bf16)((v.w - mu) * rstd * gv.w + bv.w);
}

// ---------------------------------------------------------------- GEMM 128x128, counted-vmcnt 3-buffer ring (T3+T4)
// Per iter t: s_waitcnt vmcnt(4) lgkmcnt(0)  [tile t's 4 loads landed; my ds_reads
// of the buffer to be overwritten completed] -> raw s_barrier (NO drain) ->
// STAGE tile t+2 into buf (t+2)%3 -> ds_read/MFMA tile t. Loads stay in flight
// across barriers (depth 2 = 8 outstanding). Only in-loop VMEM = staging loads,
// so the vmcnt count is exact; "memory" clobbers pin epilogue loads after loop.
// EPI 0: +bias->bf16 | EPI 1: +bias+resid->fp32 | EPI 2: +bias+QuickGELU->bf16
template <int EPI>
__global__ __launch_bounds__(256, 2) void gemm_bt(
    const bf16* __restrict__ A, const bf16* __restrict__ B,
    const float* __restrict__ bias, const float* __restrict__ resid,
    float* __restrict__ outF, bf16* __restrict__ outB,
    int M, int N, int K) {
  __shared__ bf16 As[3][128 * 32];
  __shared__ bf16 Bs[3][128 * 32];
  const int tid = threadIdx.x;
  const int lane = tid & 63, w = tid >> 6;
  const int wm = w >> 1, wn = w & 1;
  const int ql = lane & 15, lg = lane >> 4;
  const int m0 = blockIdx.x * 128, n0 = blockIdx.y * 128;

  ffrag acc[4][4];
#pragma unroll
  for (int i = 0; i < 4; i++)
#pragma unroll
    for (int j = 0; j < 4; j++) acc[i][j] = ffrag{0.f, 0.f, 0.f, 0.f};

  const int r0 = tid >> 2;
  const int jsw = (tid & 3) ^ (r0 & 3);
  const bf16* a0 = A + (size_t)(m0 + r0) * K + jsw * 8;
  const bf16* a1 = A + (size_t)(m0 + 64 + r0) * K + jsw * 8;
  const bf16* b0 = B + (size_t)(n0 + r0) * K + jsw * 8;
  const bf16* b1 = B + (size_t)(n0 + 64 + r0) * K + jsw * 8;
  const int lo = w * 512;

  auto STAGE = [&](int bs, int kk) {
    gload_lds16(a0 + kk, &As[bs][lo]);
    gload_lds16(a1 + kk, &As[bs][2048 + lo]);
    gload_lds16(b0 + kk, &Bs[bs][lo]);
    gload_lds16(b1 + kk, &Bs[bs][2048 + lo]);
  };

  STAGE(0, 0);
  STAGE(1, 32);

  int cur = 0;
  for (int k0 = 0; k0 < K; k0 += 32) {
    if (k0 + 32 < K) {
      asm volatile("s_waitcnt vmcnt(4) lgkmcnt(0)" ::: "memory");
    } else {
      asm volatile("s_waitcnt vmcnt(0) lgkmcnt(0)" ::: "memory");
    }
    __builtin_amdgcn_s_barrier();
    if (k0 + 64 < K) {
      int nb = cur + 2; if (nb >= 3) nb -= 3;
      STAGE(nb, k0 + 64);
    }
    bfrag af[4], bfr[4];
#pragma unroll
    for (int i = 0; i < 4; i++) {
      const int row = wm * 64 + i * 16 + ql;
      af[i] = *(const bfrag*)&As[cur][row * 32 + ((lg ^ (row & 3)) * 8)];
    }
#pragma unroll
    for (int j = 0; j < 4; j++) {
      const int row = wn * 64 + j * 16 + ql;
      bfr[j] = *(const bfrag*)&Bs[cur][row * 32 + ((lg ^ (row & 3)) * 8)];
    }
#pragma unroll
    for (int i = 0; i < 4; i++)
#pragma unroll
      for (int j = 0; j < 4; j++)
        acc[i][j] = mfma16(af[i], bfr[j], acc[i][j]);
    cur = (cur + 1 == 3) ? 0 : (cur + 1);
  }
  asm volatile("" ::: "memory");

#pragma unroll
  for (int i = 0; i < 4; i++) {
    const int row = m0 + wm * 64 + i * 16 + lg * 4;
#pragma unroll
    for (int j = 0; j < 4; j++) {
      const int col = n0 + wn * 64 + j * 16 + ql;
      const float bv = bias[col];
#pragma unroll
      for (int r = 0; r < 4; r++) {
        float v = acc[i][j][r] + bv;
        const size_t idx = (size_t)(row + r) * N + col;
        if (EPI == 0) {
          outB[idx] = (bf16)v;
        } else if (EPI == 1) {
          outF[idx] = v + resid[idx];
        } else {
          outB[idx] = (bf16)(v / (1.0f + __expf(-1.702f * v)));
        }
      }
    }
  }
}

// ---------------------------------------------------------------- V transpose: qkv V-part -> VT[b][h][d][s]
__global__ __launch_bounds__(256) void transpose_v(const bf16* __restrict__ qkv,
                                                   bf16* __restrict__ vt) {
  __shared__ bf16 T[64 * 66];   // [s][d], stride 66 els
  const int tid = threadIdx.x;
  const int bh = blockIdx.y, b = bh >> 4, h = bh & 15;
  const int s0 = blockIdx.x * 64;
  const bf16* src = qkv + (size_t)b * SEQ * 3072 + 2048 + h * 64;

  const int sl = tid >> 3, c = tid & 7;
#pragma unroll
  for (int p = 0; p < 2; p++) {
    const int s = sl + p * 32;
    const bfrag v = *(const bfrag*)(src + (size_t)(s0 + s) * 3072 + c * 8);
#pragma unroll
    for (int e = 0; e < 8; e++) T[s * 66 + c * 8 + e] = v[e];
  }
  __syncthreads();
  bf16* dst = vt + (size_t)bh * 64 * 1024;
#pragma unroll
  for (int p = 0; p < 2; p++) {
    const int d = sl + p * 32;
    bfrag o;
#pragma unroll
    for (int e = 0; e < 8; e++) o[e] = T[(c * 8 + e) * 66 + d];
    *(bfrag*)(dst + (size_t)d * 1024 + s0 + c * 8) = o;
  }
}

// ---------------------------------------------------------------- flash attention v5
// KVBLK=128, log2 softmax, T13 defer-max, K+V LDS-staged (3-bit XOR swizzle),
// lane-local lrun partials with a single epilogue reduce.
__global__ __launch_bounds__(256, 3) void flash_attn(const bf16* __restrict__ qkv,
                                                     const bf16* __restrict__ vt,
                                                     bf16* __restrict__ o) {
  __shared__ bf16 Kl[128 * 64];       // 16 KB, [kv][64 d]
  __shared__ bf16 Vl[64 * 128];       // 16 KB, [d][128 kv]
  __shared__ bf16 Pl[4 * 16 * 136];   // 17 KB, per-wave [16 q][128 kv] stride 136
  const int tid = threadIdx.x, lane = tid & 63, wid = tid >> 6;
  const int ql = lane & 15, lg = lane >> 4;
  const int bh = blockIdx.y, b = bh >> 4, h = bh & 15;
  const int qrow0 = blockIdx.x * 64 + wid * 16;
  const size_t headq = (size_t)b * SEQ * 3072 + (size_t)h * 64;

  const bf16* qp = qkv + headq + (size_t)(qrow0 + ql) * 3072 + lg * 8;
  const bfrag q0 = *(const bfrag*)qp;
  const bfrag q1 = *(const bfrag*)(qp + 32);

  float mrun[4], lrun[4];
  ffrag oacc[4];
#pragma unroll
  for (int r = 0; r < 4; r++) { mrun[r] = -1e30f; lrun[r] = 0.0f; }
#pragma unroll
  for (int f = 0; f < 4; f++) oacc[f] = ffrag{0.f, 0.f, 0.f, 0.f};

  const int kr0 = tid >> 3;
  const int kjsw = ((tid & 7) ^ (kr0 & 7)) * 8;
  const bf16* kp = qkv + headq + 1024 + (size_t)kr0 * 3072 + kjsw;
  const int vr_ = tid >> 4, vlc = tid & 15;
  const bf16* vhead = vt + (size_t)bh * 64 * 1024;
  bf16* Pw = Pl + wid * 2176;

  for (int kt = 0; kt < SEQ; kt += 128) {
#pragma unroll
    for (int pp = 0; pp < 4; pp++)
      gload_lds16(kp + (size_t)(kt + pp * 32) * 3072, &Kl[pp * 2048 + tid * 8]);
#pragma unroll
    for (int pp = 0; pp < 4; pp++) {
      const int vr = pp * 16 + vr_;
      const int gc = vlc ^ (vr & 7);
      gload_lds16(vhead + (size_t)vr * 1024 + kt + gc * 8, &Vl[(pp * 256 + tid) * 8]);
    }
    __syncthreads();

    // QK^T: 8 subtiles of 16 keys
    ffrag sa[8];
    __builtin_amdgcn_s_setprio(1);
#pragma unroll
    for (int sub = 0; sub < 8; sub++) {
      const int krow = sub * 16 + ql;
      const int r7 = krow & 7;
      const bfrag kf0 = *(const bfrag*)&Kl[krow * 64 + ((lg ^ r7) * 8)];
      const bfrag kf1 = *(const bfrag*)&Kl[krow * 64 + (((lg + 4) ^ r7) * 8)];
      ffrag s4 = ffrag{0.f, 0.f, 0.f, 0.f};
      s4 = mfma16(q0, kf0, s4);
      s4 = mfma16(q1, kf1, s4);
      sa[sub] = s4;
    }
    __builtin_amdgcn_s_setprio(0);

    // lane-local row maxima
    float lmax[4];
#pragma unroll
    for (int r = 0; r < 4; r++) {
      float m = sa[0][r];
#pragma unroll
      for (int sub = 1; sub < 8; sub++) m = fmaxf(m, sa[sub][r]);
      lmax[r] = m;
    }
    // T13 defer-max: skip max-reduce + rescale unless some row grew > 8 (log2 units)
    bool ok = (lmax[0] - mrun[0] <= 8.0f) && (lmax[1] - mrun[1] <= 8.0f) &&
              (lmax[2] - mrun[2] <= 8.0f) && (lmax[3] - mrun[3] <= 8.0f);
    if (!__all(ok)) {
#pragma unroll
      for (int r = 0; r < 4; r++) {
        float mx = lmax[r];
        mx = fmaxf(mx, __shfl_xor(mx, 1));
        mx = fmaxf(mx, __shfl_xor(mx, 2));
        mx = fmaxf(mx, __shfl_xor(mx, 4));
        mx = fmaxf(mx, __shfl_xor(mx, 8));
        const float mnew = fmaxf(mrun[r], mx);
        const float corr = exp2f(mrun[r] - mnew);  // uniform across ql-group
        lrun[r] *= corr;
#pragma unroll
        for (int f = 0; f < 4; f++) oacc[f][r] *= corr;
        mrun[r] = mnew;
      }
    }
    // P = 2^(s - mrun); accumulate lane-local partial sums only
#pragma unroll
    for (int r = 0; r < 4; r++) {
      float srow = 0.f;
      bf16* prow = Pw + (lg * 4 + r) * 136;
#pragma unroll
      for (int sub = 0; sub < 8; sub++) {
        const float pv = exp2f(sa[sub][r] - mrun[r]);
        srow += pv;
        prow[sub * 16 + ql] = (bf16)pv;
      }
      lrun[r] += srow;
    }

    // PV: A = P (q=ql, kv chunk kc*32+lg*8), B = V^T rows d=f*16+ql from LDS
    bfrag pa[4];
#pragma unroll
    for (int kc = 0; kc < 4; kc++)
      pa[kc] = *(const bfrag*)&Pw[ql * 136 + kc * 32 + lg * 8];
    __builtin_amdgcn_s_setprio(1);
#pragma unroll
    for (int f = 0; f < 4; f++) {
      const int vrow = f * 16 + ql;
      const int r7 = vrow & 7;
#pragma unroll
      for (int kc = 0; kc < 4; kc++) {
        const bfrag vf = *(const bfrag*)&Vl[vrow * 128 + (((kc * 4 + lg) ^ r7) * 8)];
        oacc[f] = mfma16(pa[kc], vf, oacc[f]);
      }
    }
    __builtin_amdgcn_s_setprio(0);
    __syncthreads();
  }

  // epilogue: one row-sum reduce, then scale
  float rinv[4];
#pragma unroll
  for (int r = 0; r < 4; r++) {
    float ls = lrun[r];
    ls += __shfl_xor(ls, 1);
    ls += __shfl_xor(ls, 2);
    ls += __shfl_xor(ls, 4);
    ls += __shfl_xor(ls, 8);
    rinv[r] = 1.0f / ls;
  }
#pragma unroll
  for (int f = 0; f < 4; f++) {
#pragma unroll
    for (int r = 0; r < 4; r++) {
      const size_t orow = (size_t)b * SEQ + qrow0 + lg * 4 + r;
      o[orow * 1024 + h * 64 + f * 16 + ql] = (bf16)(oacc[f][r] * rinv[r]);
    }
  }
}

// ---------------------------------------------------------------- launch
extern "C" void kernel_launch(void* const* d_in, const int* in_sizes, int n_in,
                              void* d_out, int out_size, void* d_ws, size_t ws_size,
                              hipStream_t stream) {
  (void)in_sizes; (void)n_in; (void)out_size; (void)ws_size;
  const float* x      = (const float*)d_in[0];
  const float* in_w   = (const float*)d_in[1];
  const float* in_b   = (const float*)d_in[2];
  const float* out_w  = (const float*)d_in[3];
  const float* out_b  = (const float*)d_in[4];
  const float* ln1_g  = (const float*)d_in[5];
  const float* ln1_b  = (const float*)d_in[6];
  const float* fc_w   = (const float*)d_in[7];
  const float* fc_b   = (const float*)d_in[8];
  const float* proj_w = (const float*)d_in[9];
  const float* proj_b = (const float*)d_in[10];
  const float* ln2_g  = (const float*)d_in[11];
  const float* ln2_b  = (const float*)d_in[12];
  float* out = (float*)d_out;

  char* p = (char*)d_ws;
  auto alloc = [&](size_t bytes) { char* r = p; p += (bytes + 255) & ~255ull; return r; };
  bf16* w_qkv  = (bf16*)alloc((size_t)3072 * 1024 * 2);
  bf16* w_out  = (bf16*)alloc((size_t)1024 * 1024 * 2);
  bf16* w_fc   = (bf16*)alloc((size_t)4096 * 1024 * 2);
  bf16* w_proj = (bf16*)alloc((size_t)1024 * 4096 * 2);
  float* b_qkv = (float*)alloc((size_t)3072 * 4);
  bf16* hbuf   = (bf16*)alloc((size_t)NTOK * 1024 * 2);   // LN1 out; reused as LN2 out
  float* x2    = (float*)alloc((size_t)NTOK * 1024 * 4);
  bf16* qkv    = (bf16*)alloc((size_t)NTOK * 3072 * 2);
  bf16* aout   = (bf16*)alloc((size_t)NTOK * 1024 * 2);
  bf16* ubuf   = qkv;              // aliases qkv+aout (both dead by GEMM3)
  bf16* vtb    = (bf16*)x2;        // VT [64 bh][64 d][1024 s] = 8MB; x2 written only after flash

  // fold head-scaling AND log2(e) (log2-domain softmax) into q weights+bias
  const float scaling = 0.125f * 1.44269504089f;
  convert_all<<<dim3(1024, 4), 256, 0, stream>>>(
      in_w, w_qkv, 3072 * 1024 / 4,
      out_w, w_out, 1024 * 1024 / 4,
      fc_w, w_fc, 4096 * 1024 / 4,
      proj_w, w_proj, 4096 * 1024 / 4,
      scaling, 1024 * 1024 / 4);
  scale_bias<<<12, 256, 0, stream>>>(in_b, b_qkv, 3072, 1024, scaling);

  ln_row<<<NTOK, 256, 0, stream>>>(x, ln1_g, ln1_b, hbuf);
  gemm_bt<0><<<dim3(32, 24), 256, 0, stream>>>(hbuf, w_qkv, b_qkv, nullptr,
                                               nullptr, qkv, NTOK, 3072, 1024);
  transpose_v<<<dim3(16, 64), 256, 0, stream>>>(qkv, vtb);
  flash_attn<<<dim3(16, 64), 256, 0, stream>>>(qkv, vtb, aout);
  gemm_bt<1><<<dim3(32, 8), 256, 0, stream>>>(aout, w_out, out_b, x,
                                              x2, nullptr, NTOK, 1024, 1024);
  ln_row<<<NTOK, 256, 0, stream>>>(x2, ln2_g, ln2_b, hbuf);
  gemm_bt<2><<<dim3(32, 32), 256, 0, stream>>>(hbuf, w_fc, fc_b, nullptr,
                                               nullptr, ubuf, NTOK, 4096, 1024);
  gemm_bt<1><<<dim3(32, 8), 256, 0, stream>>>(ubuf, w_proj, proj_b, x2,
                                              out, nullptr, NTOK, 1024, 4096);
}

// Round 9
// 231.467 us; speedup vs baseline: 1.1927x; 1.1927x over previous
//
#include <hip/hip_runtime.h>
#include <math.h>

#define D_MODEL 1024
#define SEQ     1024
#define BATCH   4
#define NTOK    (BATCH * SEQ)   // 4096

typedef __bf16 bf16;
using bfrag = __attribute__((ext_vector_type(8))) __bf16;
using ffrag = __attribute__((ext_vector_type(4))) float;

__device__ __forceinline__ ffrag mfma16(bfrag a, bfrag b, ffrag c) {
  return __builtin_amdgcn_mfma_f32_16x16x32_bf16(a, b, c, 0, 0, 0);
}

__device__ __forceinline__ void gload_lds16(const void* g, void* l) {
  __builtin_amdgcn_global_load_lds(
      (const __attribute__((address_space(1))) void*)g,
      (__attribute__((address_space(3))) void*)l, 16, 0, 0);
}

// XCD-aware bijective block remap (T1): consecutive-newflat blocks land on the
// same XCD (dispatch round-robins original flat % 8), giving each XCD a
// contiguous slice of the n-dimension -> B-panel becomes L2-resident per XCD.
// Requires nwg % 8 == 0 (all our grids satisfy this).
__device__ __forceinline__ int xcd_remap(int flat, int nwg) {
  return (flat & 7) * (nwg >> 3) + (flat >> 3);
}

// ---------------------------------------------------------------- all weights fp32 -> bf16 (one launch)
__global__ void convert_all(const float* __restrict__ s0, bf16* __restrict__ d0, int n0,
                            const float* __restrict__ s1, bf16* __restrict__ d1, int n1,
                            const float* __restrict__ s2, bf16* __restrict__ d2, int n2,
                            const float* __restrict__ s3, bf16* __restrict__ d3, int n3,
                            float scale, int limit0) {
  const float* src; bf16* dst; int n; int limit = 0;
  switch (blockIdx.y) {
    case 0: src = s0; dst = d0; n = n0; limit = limit0; break;
    case 1: src = s1; dst = d1; n = n1; break;
    case 2: src = s2; dst = d2; n = n2; break;
    default: src = s3; dst = d3; n = n3; break;
  }
  int i = blockIdx.x * blockDim.x + threadIdx.x;
  const int stride = gridDim.x * blockDim.x;
  for (; i < n; i += stride) {
    float4 v = ((const float4*)src)[i];
    float sc = (i < limit) ? scale : 1.0f;
    bf16* d = dst + (size_t)i * 4;
    d[0] = (bf16)(v.x * sc); d[1] = (bf16)(v.y * sc);
    d[2] = (bf16)(v.z * sc); d[3] = (bf16)(v.w * sc);
  }
}

__global__ void scale_bias(const float* __restrict__ src, float* __restrict__ dst,
                           int n, int limit, float scale) {
  int i = blockIdx.x * blockDim.x + threadIdx.x;
  if (i < n) dst[i] = src[i] * (i < limit ? scale : 1.0f);
}

// ---------------------------------------------------------------- LayerNorm (fp32 in, bf16 out)
__global__ __launch_bounds__(256) void ln_row(const float* __restrict__ x,
                                              const float* __restrict__ gamma,
                                              const float* __restrict__ beta,
                                              bf16* __restrict__ out) {
  const int row = blockIdx.x, tid = threadIdx.x;
  const float4 v = ((const float4*)(x + (size_t)row * D_MODEL))[tid];
  float s  = v.x + v.y + v.z + v.w;
  float ss = v.x * v.x + v.y * v.y + v.z * v.z + v.w * v.w;
#pragma unroll
  for (int off = 32; off >= 1; off >>= 1) {
    s  += __shfl_xor(s, off);
    ss += __shfl_xor(ss, off);
  }
  __shared__ float rs[4], rss[4];
  const int w = tid >> 6;
  if ((tid & 63) == 0) { rs[w] = s; rss[w] = ss; }
  __syncthreads();
  s  = rs[0] + rs[1] + rs[2] + rs[3];
  ss = rss[0] + rss[1] + rss[2] + rss[3];
  const float mu   = s * (1.0f / D_MODEL);
  const float var  = ss * (1.0f / D_MODEL) - mu * mu;
  const float rstd = rsqrtf(var + 1e-5f);
  const float4 gv = ((const float4*)gamma)[tid];
  const float4 bv = ((const float4*)beta)[tid];
  bf16* o = out + (size_t)row * D_MODEL + tid * 4;
  o[0] = (bf16)((v.x - mu) * rstd * gv.x + bv.x);
  o[1] = (bf16)((v.y - mu) * rstd * gv.y + bv.y);
  o[2] = (bf16)((v.z - mu) * rstd * gv.z + bv.z);
  o[3] = (bf16)((v.w - mu) * rstd * gv.w + bv.w);
}

// ---------------------------------------------------------------- GEMM 128x128 (QKV, FC) — round-6 2-phase drain
// Chunk swizzle (r>>1)&3 balances banks: per b128 wave-read each 4-bank group
// gets exactly 8 dwords (old r&3 variant measured 4.2M conflict cycles).
// EPI 0: +bias->bf16 | EPI 1: +bias+resid->fp32 | EPI 2: +bias+QuickGELU->bf16
template <int EPI>
__global__ __launch_bounds__(256, 2) void gemm_bt(
    const bf16* __restrict__ A, const bf16* __restrict__ B,
    const float* __restrict__ bias, const float* __restrict__ resid,
    float* __restrict__ outF, bf16* __restrict__ outB,
    int M, int N, int K) {
  __shared__ bf16 As[2][128 * 32];
  __shared__ bf16 Bs[2][128 * 32];
  const int tid = threadIdx.x;
  const int lane = tid & 63, w = tid >> 6;
  const int wm = w >> 1, wn = w & 1;
  const int ql = lane & 15, lg = lane >> 4;
  const int nwg = gridDim.x * gridDim.y;
  const int flat = xcd_remap(blockIdx.y * gridDim.x + blockIdx.x, nwg);
  const int m0 = (flat % gridDim.x) * 128, n0 = (flat / gridDim.x) * 128;

  ffrag acc[4][4];
#pragma unroll
  for (int i = 0; i < 4; i++)
#pragma unroll
    for (int j = 0; j < 4; j++) acc[i][j] = ffrag{0.f, 0.f, 0.f, 0.f};

  const int r0 = tid >> 2;
  const int jsw = (tid & 3) ^ ((r0 >> 1) & 3);
  const bf16* a0 = A + (size_t)(m0 + r0) * K + jsw * 8;
  const bf16* a1 = A + (size_t)(m0 + 64 + r0) * K + jsw * 8;
  const bf16* b0 = B + (size_t)(n0 + r0) * K + jsw * 8;
  const bf16* b1 = B + (size_t)(n0 + 64 + r0) * K + jsw * 8;
  const int lo = w * 512;

  auto STAGE = [&](int bs, int kk) {
    gload_lds16(a0 + kk, &As[bs][lo]);
    gload_lds16(a1 + kk, &As[bs][2048 + lo]);
    gload_lds16(b0 + kk, &Bs[bs][lo]);
    gload_lds16(b1 + kk, &Bs[bs][2048 + lo]);
  };

  STAGE(0, 0);
  __syncthreads();

  int cur = 0;
  for (int k0 = 0; k0 < K; k0 += 32) {
    if (k0 + 32 < K) STAGE(cur ^ 1, k0 + 32);
    bfrag af[4], bfr[4];
#pragma unroll
    for (int i = 0; i < 4; i++) {
      const int row = wm * 64 + i * 16 + ql;
      af[i] = *(const bfrag*)&As[cur][row * 32 + ((lg ^ ((row >> 1) & 3)) * 8)];
    }
#pragma unroll
    for (int j = 0; j < 4; j++) {
      const int row = wn * 64 + j * 16 + ql;
      bfr[j] = *(const bfrag*)&Bs[cur][row * 32 + ((lg ^ ((row >> 1) & 3)) * 8)];
    }
#pragma unroll
    for (int i = 0; i < 4; i++)
#pragma unroll
      for (int j = 0; j < 4; j++)
        acc[i][j] = mfma16(af[i], bfr[j], acc[i][j]);
    __syncthreads();
    cur ^= 1;
  }

#pragma unroll
  for (int i = 0; i < 4; i++) {
    const int row = m0 + wm * 64 + i * 16 + lg * 4;
#pragma unroll
    for (int j = 0; j < 4; j++) {
      const int col = n0 + wn * 64 + j * 16 + ql;
      const float bv = bias[col];
#pragma unroll
      for (int r = 0; r < 4; r++) {
        float v = acc[i][j][r] + bv;
        const size_t idx = (size_t)(row + r) * N + col;
        if (EPI == 0) {
          outB[idx] = (bf16)v;
        } else if (EPI == 1) {
          outF[idx] = v + resid[idx];
        } else {
          outB[idx] = (bf16)(v / (1.0f + __expf(-1.702f * v)));
        }
      }
    }
  }
}

// ---------------------------------------------------------------- GEMM 64x64 (out, proj) — round-6 proven + XCD remap
template <int EPI>
__global__ __launch_bounds__(256, 4) void gemm_bt64(
    const bf16* __restrict__ A, const bf16* __restrict__ B,
    const float* __restrict__ bias, const float* __restrict__ resid,
    float* __restrict__ outF, bf16* __restrict__ outB,
    int M, int N, int K) {
  __shared__ bf16 As[2][64 * 64];
  __shared__ bf16 Bs[2][64 * 64];
  const int tid = threadIdx.x;
  const int lane = tid & 63, w = tid >> 6;
  const int wm = w >> 1, wn = w & 1;
  const int ql = lane & 15, lg = lane >> 4;
  const int nwg = gridDim.x * gridDim.y;
  const int flat = xcd_remap(blockIdx.y * gridDim.x + blockIdx.x, nwg);
  const int m0 = (flat % gridDim.x) * 64, n0 = (flat / gridDim.x) * 64;

  ffrag acc[2][2];
#pragma unroll
  for (int i = 0; i < 2; i++)
#pragma unroll
    for (int j = 0; j < 2; j++) acc[i][j] = ffrag{0.f, 0.f, 0.f, 0.f};

  const int r0 = tid >> 3;
  const int jsw = ((tid & 7) ^ (r0 & 7)) * 8;
  const bf16* a0 = A + (size_t)(m0 + r0) * K + jsw;
  const bf16* a1 = A + (size_t)(m0 + 32 + r0) * K + jsw;
  const bf16* b0 = B + (size_t)(n0 + r0) * K + jsw;
  const bf16* b1 = B + (size_t)(n0 + 32 + r0) * K + jsw;
  const int lo = tid * 8;

  auto STAGE = [&](int bs, int kk) {
    gload_lds16(a0 + kk, &As[bs][lo]);
    gload_lds16(a1 + kk, &As[bs][2048 + lo]);
    gload_lds16(b0 + kk, &Bs[bs][lo]);
    gload_lds16(b1 + kk, &Bs[bs][2048 + lo]);
  };

  STAGE(0, 0);
  __syncthreads();

  int cur = 0;
  for (int k0 = 0; k0 < K; k0 += 64) {
    if (k0 + 64 < K) STAGE(cur ^ 1, k0 + 64);
    bfrag af[2][2], bfr[2][2];
#pragma unroll
    for (int i = 0; i < 2; i++) {
      const int row = wm * 32 + i * 16 + ql;
      const int r7 = row & 7;
#pragma unroll
      for (int kc = 0; kc < 2; kc++)
        af[i][kc] = *(const bfrag*)&As[cur][row * 64 + (((lg + 4 * kc) ^ r7) * 8)];
    }
#pragma unroll
    for (int j = 0; j < 2; j++) {
      const int row = wn * 32 + j * 16 + ql;
      const int r7 = row & 7;
#pragma unroll
      for (int kc = 0; kc < 2; kc++)
        bfr[j][kc] = *(const bfrag*)&Bs[cur][row * 64 + (((lg + 4 * kc) ^ r7) * 8)];
    }
#pragma unroll
    for (int kc = 0; kc < 2; kc++)
#pragma unroll
      for (int i = 0; i < 2; i++)
#pragma unroll
        for (int j = 0; j < 2; j++)
          acc[i][j] = mfma16(af[i][kc], bfr[j][kc], acc[i][j]);
    __syncthreads();
    cur ^= 1;
  }

#pragma unroll
  for (int i = 0; i < 2; i++) {
    const int row = m0 + wm * 32 + i * 16 + lg * 4;
#pragma unroll
    for (int j = 0; j < 2; j++) {
      const int col = n0 + wn * 32 + j * 16 + ql;
      const float bv = bias[col];
#pragma unroll
      for (int r = 0; r < 4; r++) {
        float v = acc[i][j][r] + bv;
        const size_t idx = (size_t)(row + r) * N + col;
        if (EPI == 0) {
          outB[idx] = (bf16)v;
        } else if (EPI == 1) {
          outF[idx] = v + resid[idx];
        } else {
          outB[idx] = (bf16)(v / (1.0f + __expf(-1.702f * v)));
        }
      }
    }
  }
}

// ---------------------------------------------------------------- V transpose: qkv V-part -> VT[b][h][d][s]
__global__ __launch_bounds__(256) void transpose_v(const bf16* __restrict__ qkv,
                                                   bf16* __restrict__ vt) {
  __shared__ bf16 T[64 * 66];   // [s][d], stride 66 els
  const int tid = threadIdx.x;
  const int bh = blockIdx.y, b = bh >> 4, h = bh & 15;
  const int s0 = blockIdx.x * 64;
  const bf16* src = qkv + (size_t)b * SEQ * 3072 + 2048 + h * 64;

  const int sl = tid >> 3, c = tid & 7;
#pragma unroll
  for (int p = 0; p < 2; p++) {
    const int s = sl + p * 32;
    const bfrag v = *(const bfrag*)(src + (size_t)(s0 + s) * 3072 + c * 8);
#pragma unroll
    for (int e = 0; e < 8; e++) T[s * 66 + c * 8 + e] = v[e];
  }
  __syncthreads();
  bf16* dst = vt + (size_t)bh * 64 * 1024;
#pragma unroll
  for (int p = 0; p < 2; p++) {
    const int d = sl + p * 32;
    bfrag o;
#pragma unroll
    for (int e = 0; e < 8; e++) o[e] = T[(c * 8 + e) * 66 + d];
    *(bfrag*)(dst + (size_t)d * 1024 + s0 + c * 8) = o;
  }
}

// ---------------------------------------------------------------- flash attention v5 + XCD remap
// KVBLK=128, log2 softmax, T13 defer-max, K+V LDS-staged (3-bit XOR swizzle),
// lane-local lrun partials with a single epilogue reduce.
__global__ __launch_bounds__(256, 3) void flash_attn(const bf16* __restrict__ qkv,
                                                     const bf16* __restrict__ vt,
                                                     bf16* __restrict__ o) {
  __shared__ bf16 Kl[128 * 64];       // 16 KB, [kv][64 d]
  __shared__ bf16 Vl[64 * 128];       // 16 KB, [d][128 kv]
  __shared__ bf16 Pl[4 * 16 * 136];   // 17 KB, per-wave [16 q][128 kv] stride 136
  const int tid = threadIdx.x, lane = tid & 63, wid = tid >> 6;
  const int ql = lane & 15, lg = lane >> 4;
  const int flat = xcd_remap(blockIdx.y * 16 + blockIdx.x, 1024);
  const int bh = flat >> 4, b = bh >> 4, h = bh & 15;
  const int qrow0 = (flat & 15) * 64 + wid * 16;
  const size_t headq = (size_t)b * SEQ * 3072 + (size_t)h * 64;

  const bf16* qp = qkv + headq + (size_t)(qrow0 + ql) * 3072 + lg * 8;
  const bfrag q0 = *(const bfrag*)qp;
  const bfrag q1 = *(const bfrag*)(qp + 32);

  float mrun[4], lrun[4];
  ffrag oacc[4];
#pragma unroll
  for (int r = 0; r < 4; r++) { mrun[r] = -1e30f; lrun[r] = 0.0f; }
#pragma unroll
  for (int f = 0; f < 4; f++) oacc[f] = ffrag{0.f, 0.f, 0.f, 0.f};

  const int kr0 = tid >> 3;
  const int kjsw = ((tid & 7) ^ (kr0 & 7)) * 8;
  const bf16* kp = qkv + headq + 1024 + (size_t)kr0 * 3072 + kjsw;
  const int vr_ = tid >> 4, vlc = tid & 15;
  const bf16* vhead = vt + (size_t)bh * 64 * 1024;
  bf16* Pw = Pl + wid * 2176;

  for (int kt = 0; kt < SEQ; kt += 128) {
#pragma unroll
    for (int pp = 0; pp < 4; pp++)
      gload_lds16(kp + (size_t)(kt + pp * 32) * 3072, &Kl[pp * 2048 + tid * 8]);
#pragma unroll
    for (int pp = 0; pp < 4; pp++) {
      const int vr = pp * 16 + vr_;
      const int gc = vlc ^ (vr & 7);
      gload_lds16(vhead + (size_t)vr * 1024 + kt + gc * 8, &Vl[(pp * 256 + tid) * 8]);
    }
    __syncthreads();

    // QK^T: 8 subtiles of 16 keys
    ffrag sa[8];
    __builtin_amdgcn_s_setprio(1);
#pragma unroll
    for (int sub = 0; sub < 8; sub++) {
      const int krow = sub * 16 + ql;
      const int r7 = krow & 7;
      const bfrag kf0 = *(const bfrag*)&Kl[krow * 64 + ((lg ^ r7) * 8)];
      const bfrag kf1 = *(const bfrag*)&Kl[krow * 64 + (((lg + 4) ^ r7) * 8)];
      ffrag s4 = ffrag{0.f, 0.f, 0.f, 0.f};
      s4 = mfma16(q0, kf0, s4);
      s4 = mfma16(q1, kf1, s4);
      sa[sub] = s4;
    }
    __builtin_amdgcn_s_setprio(0);

    // lane-local row maxima
    float lmax[4];
#pragma unroll
    for (int r = 0; r < 4; r++) {
      float m = sa[0][r];
#pragma unroll
      for (int sub = 1; sub < 8; sub++) m = fmaxf(m, sa[sub][r]);
      lmax[r] = m;
    }
    // T13 defer-max: skip max-reduce + rescale unless some row grew > 8 (log2 units)
    bool ok = (lmax[0] - mrun[0] <= 8.0f) && (lmax[1] - mrun[1] <= 8.0f) &&
              (lmax[2] - mrun[2] <= 8.0f) && (lmax[3] - mrun[3] <= 8.0f);
    if (!__all(ok)) {
#pragma unroll
      for (int r = 0; r < 4; r++) {
        float mx = lmax[r];
        mx = fmaxf(mx, __shfl_xor(mx, 1));
        mx = fmaxf(mx, __shfl_xor(mx, 2));
        mx = fmaxf(mx, __shfl_xor(mx, 4));
        mx = fmaxf(mx, __shfl_xor(mx, 8));
        const float mnew = fmaxf(mrun[r], mx);
        const float corr = exp2f(mrun[r] - mnew);  // uniform across ql-group
        lrun[r] *= corr;
#pragma unroll
        for (int f = 0; f < 4; f++) oacc[f][r] *= corr;
        mrun[r] = mnew;
      }
    }
    // P = 2^(s - mrun); accumulate lane-local partial sums only
#pragma unroll
    for (int r = 0; r < 4; r++) {
      float srow = 0.f;
      bf16* prow = Pw + (lg * 4 + r) * 136;
#pragma unroll
      for (int sub = 0; sub < 8; sub++) {
        const float pv = exp2f(sa[sub][r] - mrun[r]);
        srow += pv;
        prow[sub * 16 + ql] = (bf16)pv;
      }
      lrun[r] += srow;
    }

    // PV: A = P (q=ql, kv chunk kc*32+lg*8), B = V^T rows d=f*16+ql from LDS
    bfrag pa[4];
#pragma unroll
    for (int kc = 0; kc < 4; kc++)
      pa[kc] = *(const bfrag*)&Pw[ql * 136 + kc * 32 + lg * 8];
    __builtin_amdgcn_s_setprio(1);
#pragma unroll
    for (int f = 0; f < 4; f++) {
      const int vrow = f * 16 + ql;
      const int r7 = vrow & 7;
#pragma unroll
      for (int kc = 0; kc < 4; kc++) {
        const bfrag vf = *(const bfrag*)&Vl[vrow * 128 + (((kc * 4 + lg) ^ r7) * 8)];
        oacc[f] = mfma16(pa[kc], vf, oacc[f]);
      }
    }
    __builtin_amdgcn_s_setprio(0);
    __syncthreads();
  }

  // epilogue: one row-sum reduce, then scale
  float rinv[4];
#pragma unroll
  for (int r = 0; r < 4; r++) {
    float ls = lrun[r];
    ls += __shfl_xor(ls, 1);
    ls += __shfl_xor(ls, 2);
    ls += __shfl_xor(ls, 4);
    ls += __shfl_xor(ls, 8);
    rinv[r] = 1.0f / ls;
  }
#pragma unroll
  for (int f = 0; f < 4; f++) {
#pragma unroll
    for (int r = 0; r < 4; r++) {
      const size_t orow = (size_t)b * SEQ + qrow0 + lg * 4 + r;
      o[orow * 1024 + h * 64 + f * 16 + ql] = (bf16)(oacc[f][r] * rinv[r]);
    }
  }
}

// ---------------------------------------------------------------- launch
extern "C" void kernel_launch(void* const* d_in, const int* in_sizes, int n_in,
                              void* d_out, int out_size, void* d_ws, size_t ws_size,
                              hipStream_t stream) {
  (void)in_sizes; (void)n_in; (void)out_size; (void)ws_size;
  const float* x      = (const float*)d_in[0];
  const float* in_w   = (const float*)d_in[1];
  const float* in_b   = (const float*)d_in[2];
  const float* out_w  = (const float*)d_in[3];
  const float* out_b  = (const float*)d_in[4];
  const float* ln1_g  = (const float*)d_in[5];
  const float* ln1_b  = (const float*)d_in[6];
  const float* fc_w   = (const float*)d_in[7];
  const float* fc_b   = (const float*)d_in[8];
  const float* proj_w = (const float*)d_in[9];
  const float* proj_b = (const float*)d_in[10];
  const float* ln2_g  = (const float*)d_in[11];
  const float* ln2_b  = (const float*)d_in[12];
  float* out = (float*)d_out;

  char* p = (char*)d_ws;
  auto alloc = [&](size_t bytes) { char* r = p; p += (bytes + 255) & ~255ull; return r; };
  bf16* w_qkv  = (bf16*)alloc((size_t)3072 * 1024 * 2);
  bf16* w_out  = (bf16*)alloc((size_t)1024 * 1024 * 2);
  bf16* w_fc   = (bf16*)alloc((size_t)4096 * 1024 * 2);
  bf16* w_proj = (bf16*)alloc((size_t)1024 * 4096 * 2);
  float* b_qkv = (float*)alloc((size_t)3072 * 4);
  bf16* hbuf   = (bf16*)alloc((size_t)NTOK * 1024 * 2);   // LN1 out; reused as LN2 out
  float* x2    = (float*)alloc((size_t)NTOK * 1024 * 4);
  bf16* qkv    = (bf16*)alloc((size_t)NTOK * 3072 * 2);
  bf16* aout   = (bf16*)alloc((size_t)NTOK * 1024 * 2);
  bf16* ubuf   = qkv;              // aliases qkv+aout (both dead by GEMM3)
  bf16* vtb    = (bf16*)x2;        // VT [64 bh][64 d][1024 s] = 8MB; x2 written only after flash

  // fold head-scaling AND log2(e) (log2-domain softmax) into q weights+bias
  const float scaling = 0.125f * 1.44269504089f;
  convert_all<<<dim3(1024, 4), 256, 0, stream>>>(
      in_w, w_qkv, 3072 * 1024 / 4,
      out_w, w_out, 1024 * 1024 / 4,
      fc_w, w_fc, 4096 * 1024 / 4,
      proj_w, w_proj, 4096 * 1024 / 4,
      scaling, 1024 * 1024 / 4);
  scale_bias<<<12, 256, 0, stream>>>(in_b, b_qkv, 3072, 1024, scaling);

  ln_row<<<NTOK, 256, 0, stream>>>(x, ln1_g, ln1_b, hbuf);
  gemm_bt<0><<<dim3(32, 24), 256, 0, stream>>>(hbuf, w_qkv, b_qkv, nullptr,
                                               nullptr, qkv, NTOK, 3072, 1024);
  transpose_v<<<dim3(16, 64), 256, 0, stream>>>(qkv, vtb);
  flash_attn<<<dim3(16, 64), 256, 0, stream>>>(qkv, vtb, aout);
  gemm_bt64<1><<<dim3(64, 16), 256, 0, stream>>>(aout, w_out, out_b, x,
                                                 x2, nullptr, NTOK, 1024, 1024);
  ln_row<<<NTOK, 256, 0, stream>>>(x2, ln2_g, ln2_b, hbuf);
  gemm_bt<2><<<dim3(32, 32), 256, 0, stream>>>(hbuf, w_fc, fc_b, nullptr,
                                               nullptr, ubuf, NTOK, 4096, 1024);
  gemm_bt64<1><<<dim3(64, 16), 256, 0, stream>>>(ubuf, w_proj, proj_b, x2,
                                                 out, nullptr, NTOK, 1024, 4096);
}

// Round 10
// 228.526 us; speedup vs baseline: 1.2080x; 1.0129x over previous
//
#include <hip/hip_runtime.h>
#include <math.h>

#define D_MODEL 1024
#define SEQ     1024
#define BATCH   4
#define NTOK    (BATCH * SEQ)   // 4096

typedef __bf16 bf16;
using bfrag = __attribute__((ext_vector_type(8))) __bf16;
using ffrag = __attribute__((ext_vector_type(4))) float;

__device__ __forceinline__ ffrag mfma16(bfrag a, bfrag b, ffrag c) {
  return __builtin_amdgcn_mfma_f32_16x16x32_bf16(a, b, c, 0, 0, 0);
}

__device__ __forceinline__ void gload_lds16(const void* g, void* l) {
  __builtin_amdgcn_global_load_lds(
      (const __attribute__((address_space(1))) void*)g,
      (__attribute__((address_space(3))) void*)l, 16, 0, 0);
}

// XCD-aware bijective block remap (T1). ONLY for GEMMs whose A-panel is small
// (<=8 MB): per-XCD A-sweeps of a 32 MB A (proj) thrash L3 (round-9: FETCH
// 57->144 MB, +3.5 us). Applied to gemm_bt (A=8MB), NOT gemm_bt64.
__device__ __forceinline__ int xcd_remap(int flat, int nwg) {
  return (flat & 7) * (nwg >> 3) + (flat >> 3);
}

// ---------------------------------------------------------------- all weights fp32 -> bf16 (one launch)
__global__ void convert_all(const float* __restrict__ s0, bf16* __restrict__ d0, int n0,
                            const float* __restrict__ s1, bf16* __restrict__ d1, int n1,
                            const float* __restrict__ s2, bf16* __restrict__ d2, int n2,
                            const float* __restrict__ s3, bf16* __restrict__ d3, int n3,
                            float scale, int limit0) {
  const float* src; bf16* dst; int n; int limit = 0;
  switch (blockIdx.y) {
    case 0: src = s0; dst = d0; n = n0; limit = limit0; break;
    case 1: src = s1; dst = d1; n = n1; break;
    case 2: src = s2; dst = d2; n = n2; break;
    default: src = s3; dst = d3; n = n3; break;
  }
  int i = blockIdx.x * blockDim.x + threadIdx.x;
  const int stride = gridDim.x * blockDim.x;
  for (; i < n; i += stride) {
    float4 v = ((const float4*)src)[i];
    float sc = (i < limit) ? scale : 1.0f;
    bf16* d = dst + (size_t)i * 4;
    d[0] = (bf16)(v.x * sc); d[1] = (bf16)(v.y * sc);
    d[2] = (bf16)(v.z * sc); d[3] = (bf16)(v.w * sc);
  }
}

__global__ void scale_bias(const float* __restrict__ src, float* __restrict__ dst,
                           int n, int limit, float scale) {
  int i = blockIdx.x * blockDim.x + threadIdx.x;
  if (i < n) dst[i] = src[i] * (i < limit ? scale : 1.0f);
}

// ---------------------------------------------------------------- LayerNorm (fp32 in, bf16 out)
__global__ __launch_bounds__(256) void ln_row(const float* __restrict__ x,
                                              const float* __restrict__ gamma,
                                              const float* __restrict__ beta,
                                              bf16* __restrict__ out) {
  const int row = blockIdx.x, tid = threadIdx.x;
  const float4 v = ((const float4*)(x + (size_t)row * D_MODEL))[tid];
  float s  = v.x + v.y + v.z + v.w;
  float ss = v.x * v.x + v.y * v.y + v.z * v.z + v.w * v.w;
#pragma unroll
  for (int off = 32; off >= 1; off >>= 1) {
    s  += __shfl_xor(s, off);
    ss += __shfl_xor(ss, off);
  }
  __shared__ float rs[4], rss[4];
  const int w = tid >> 6;
  if ((tid & 63) == 0) { rs[w] = s; rss[w] = ss; }
  __syncthreads();
  s  = rs[0] + rs[1] + rs[2] + rs[3];
  ss = rss[0] + rss[1] + rss[2] + rss[3];
  const float mu   = s * (1.0f / D_MODEL);
  const float var  = ss * (1.0f / D_MODEL) - mu * mu;
  const float rstd = rsqrtf(var + 1e-5f);
  const float4 gv = ((const float4*)gamma)[tid];
  const float4 bv = ((const float4*)beta)[tid];
  bf16* o = out + (size_t)row * D_MODEL + tid * 4;
  o[0] = (bf16)((v.x - mu) * rstd * gv.x + bv.x);
  o[1] = (bf16)((v.y - mu) * rstd * gv.y + bv.y);
  o[2] = (bf16)((v.z - mu) * rstd * gv.z + bv.z);
  o[3] = (bf16)((v.w - mu) * rstd * gv.w + bv.w);
}

// ---------------------------------------------------------------- GEMM 128x128 (QKV, FC)
// launch_bounds(256,4): target 4 blocks/CU residency (VGPR<=128, LDS 32KB both
// permit it); inter-block TLP hides the per-step vmcnt drain (round-4 mechanism).
// Chunk swizzle (r>>1)&3: per b128 wave-read each 4-bank group gets exactly
// 2 rows of each parity -> 2-way (free, m136).
// EPI 0: +bias->bf16 | EPI 1: +bias+resid->fp32 | EPI 2: +bias+QuickGELU->bf16
template <int EPI>
__global__ __launch_bounds__(256, 4) void gemm_bt(
    const bf16* __restrict__ A, const bf16* __restrict__ B,
    const float* __restrict__ bias, const float* __restrict__ resid,
    float* __restrict__ outF, bf16* __restrict__ outB,
    int M, int N, int K) {
  __shared__ bf16 As[2][128 * 32];
  __shared__ bf16 Bs[2][128 * 32];
  const int tid = threadIdx.x;
  const int lane = tid & 63, w = tid >> 6;
  const int wm = w >> 1, wn = w & 1;
  const int ql = lane & 15, lg = lane >> 4;
  const int nwg = gridDim.x * gridDim.y;
  const int flat = xcd_remap(blockIdx.y * gridDim.x + blockIdx.x, nwg);
  const int m0 = (flat % gridDim.x) * 128, n0 = (flat / gridDim.x) * 128;

  ffrag acc[4][4];
#pragma unroll
  for (int i = 0; i < 4; i++)
#pragma unroll
    for (int j = 0; j < 4; j++) acc[i][j] = ffrag{0.f, 0.f, 0.f, 0.f};

  const int r0 = tid >> 2;
  const int jsw = (tid & 3) ^ ((r0 >> 1) & 3);
  const bf16* a0 = A + (size_t)(m0 + r0) * K + jsw * 8;
  const bf16* a1 = A + (size_t)(m0 + 64 + r0) * K + jsw * 8;
  const bf16* b0 = B + (size_t)(n0 + r0) * K + jsw * 8;
  const bf16* b1 = B + (size_t)(n0 + 64 + r0) * K + jsw * 8;
  const int lo = w * 512;

  auto STAGE = [&](int bs, int kk) {
    gload_lds16(a0 + kk, &As[bs][lo]);
    gload_lds16(a1 + kk, &As[bs][2048 + lo]);
    gload_lds16(b0 + kk, &Bs[bs][lo]);
    gload_lds16(b1 + kk, &Bs[bs][2048 + lo]);
  };

  STAGE(0, 0);
  __syncthreads();

  int cur = 0;
  for (int k0 = 0; k0 < K; k0 += 32) {
    if (k0 + 32 < K) STAGE(cur ^ 1, k0 + 32);
    bfrag af[4], bfr[4];
#pragma unroll
    for (int i = 0; i < 4; i++) {
      const int row = wm * 64 + i * 16 + ql;
      af[i] = *(const bfrag*)&As[cur][row * 32 + ((lg ^ ((row >> 1) & 3)) * 8)];
    }
#pragma unroll
    for (int j = 0; j < 4; j++) {
      const int row = wn * 64 + j * 16 + ql;
      bfr[j] = *(const bfrag*)&Bs[cur][row * 32 + ((lg ^ ((row >> 1) & 3)) * 8)];
    }
#pragma unroll
    for (int i = 0; i < 4; i++)
#pragma unroll
      for (int j = 0; j < 4; j++)
        acc[i][j] = mfma16(af[i], bfr[j], acc[i][j]);
    __syncthreads();
    cur ^= 1;
  }

#pragma unroll
  for (int i = 0; i < 4; i++) {
    const int row = m0 + wm * 64 + i * 16 + lg * 4;
#pragma unroll
    for (int j = 0; j < 4; j++) {
      const int col = n0 + wn * 64 + j * 16 + ql;
      const float bv = bias[col];
#pragma unroll
      for (int r = 0; r < 4; r++) {
        float v = acc[i][j][r] + bv;
        const size_t idx = (size_t)(row + r) * N + col;
        if (EPI == 0) {
          outB[idx] = (bf16)v;
        } else if (EPI == 1) {
          outF[idx] = v + resid[idx];
        } else {
          outB[idx] = (bf16)(v / (1.0f + __expf(-1.702f * v)));
        }
      }
    }
  }
}

// ---------------------------------------------------------------- GEMM 64x64 (out, proj) — round-6 proven config
// Plain blockIdx mapping (XCD remap on 32MB-A proj thrashed L3: FETCH 57->144MB).
template <int EPI>
__global__ __launch_bounds__(256, 4) void gemm_bt64(
    const bf16* __restrict__ A, const bf16* __restrict__ B,
    const float* __restrict__ bias, const float* __restrict__ resid,
    float* __restrict__ outF, bf16* __restrict__ outB,
    int M, int N, int K) {
  __shared__ bf16 As[2][64 * 64];
  __shared__ bf16 Bs[2][64 * 64];
  const int tid = threadIdx.x;
  const int lane = tid & 63, w = tid >> 6;
  const int wm = w >> 1, wn = w & 1;
  const int ql = lane & 15, lg = lane >> 4;
  const int m0 = blockIdx.x * 64, n0 = blockIdx.y * 64;

  ffrag acc[2][2];
#pragma unroll
  for (int i = 0; i < 2; i++)
#pragma unroll
    for (int j = 0; j < 2; j++) acc[i][j] = ffrag{0.f, 0.f, 0.f, 0.f};

  const int r0 = tid >> 3;
  const int jsw = ((tid & 7) ^ (r0 & 7)) * 8;
  const bf16* a0 = A + (size_t)(m0 + r0) * K + jsw;
  const bf16* a1 = A + (size_t)(m0 + 32 + r0) * K + jsw;
  const bf16* b0 = B + (size_t)(n0 + r0) * K + jsw;
  const bf16* b1 = B + (size_t)(n0 + 32 + r0) * K + jsw;
  const int lo = tid * 8;

  auto STAGE = [&](int bs, int kk) {
    gload_lds16(a0 + kk, &As[bs][lo]);
    gload_lds16(a1 + kk, &As[bs][2048 + lo]);
    gload_lds16(b0 + kk, &Bs[bs][lo]);
    gload_lds16(b1 + kk, &Bs[bs][2048 + lo]);
  };

  STAGE(0, 0);
  __syncthreads();

  int cur = 0;
  for (int k0 = 0; k0 < K; k0 += 64) {
    if (k0 + 64 < K) STAGE(cur ^ 1, k0 + 64);
    bfrag af[2][2], bfr[2][2];
#pragma unroll
    for (int i = 0; i < 2; i++) {
      const int row = wm * 32 + i * 16 + ql;
      const int r7 = row & 7;
#pragma unroll
      for (int kc = 0; kc < 2; kc++)
        af[i][kc] = *(const bfrag*)&As[cur][row * 64 + (((lg + 4 * kc) ^ r7) * 8)];
    }
#pragma unroll
    for (int j = 0; j < 2; j++) {
      const int row = wn * 32 + j * 16 + ql;
      const int r7 = row & 7;
#pragma unroll
      for (int kc = 0; kc < 2; kc++)
        bfr[j][kc] = *(const bfrag*)&Bs[cur][row * 64 + (((lg + 4 * kc) ^ r7) * 8)];
    }
#pragma unroll
    for (int kc = 0; kc < 2; kc++)
#pragma unroll
      for (int i = 0; i < 2; i++)
#pragma unroll
        for (int j = 0; j < 2; j++)
          acc[i][j] = mfma16(af[i][kc], bfr[j][kc], acc[i][j]);
    __syncthreads();
    cur ^= 1;
  }

#pragma unroll
  for (int i = 0; i < 2; i++) {
    const int row = m0 + wm * 32 + i * 16 + lg * 4;
#pragma unroll
    for (int j = 0; j < 2; j++) {
      const int col = n0 + wn * 32 + j * 16 + ql;
      const float bv = bias[col];
#pragma unroll
      for (int r = 0; r < 4; r++) {
        float v = acc[i][j][r] + bv;
        const size_t idx = (size_t)(row + r) * N + col;
        if (EPI == 0) {
          outB[idx] = (bf16)v;
        } else if (EPI == 1) {
          outF[idx] = v + resid[idx];
        } else {
          outB[idx] = (bf16)(v / (1.0f + __expf(-1.702f * v)));
        }
      }
    }
  }
}

// ---------------------------------------------------------------- V transpose: qkv V-part -> VT[b][h][d][s]
__global__ __launch_bounds__(256) void transpose_v(const bf16* __restrict__ qkv,
                                                   bf16* __restrict__ vt) {
  __shared__ bf16 T[64 * 66];   // [s][d], stride 66 els
  const int tid = threadIdx.x;
  const int bh = blockIdx.y, b = bh >> 4, h = bh & 15;
  const int s0 = blockIdx.x * 64;
  const bf16* src = qkv + (size_t)b * SEQ * 3072 + 2048 + h * 64;

  const int sl = tid >> 3, c = tid & 7;
#pragma unroll
  for (int p = 0; p < 2; p++) {
    const int s = sl + p * 32;
    const bfrag v = *(const bfrag*)(src + (size_t)(s0 + s) * 3072 + c * 8);
#pragma unroll
    for (int e = 0; e < 8; e++) T[s * 66 + c * 8 + e] = v[e];
  }
  __syncthreads();
  bf16* dst = vt + (size_t)bh * 64 * 1024;
#pragma unroll
  for (int p = 0; p < 2; p++) {
    const int d = sl + p * 32;
    bfrag o;
#pragma unroll
    for (int e = 0; e < 8; e++) o[e] = T[(c * 8 + e) * 66 + d];
    *(bfrag*)(dst + (size_t)d * 1024 + s0 + c * 8) = o;
  }
}

// ---------------------------------------------------------------- flash attention v5 + XCD remap
// KVBLK=128, log2 softmax, T13 defer-max, K+V LDS-staged (3-bit XOR swizzle),
// lane-local lrun partials with a single epilogue reduce.
__global__ __launch_bounds__(256, 3) void flash_attn(const bf16* __restrict__ qkv,
                                                     const bf16* __restrict__ vt,
                                                     bf16* __restrict__ o) {
  __shared__ bf16 Kl[128 * 64];       // 16 KB, [kv][64 d]
  __shared__ bf16 Vl[64 * 128];       // 16 KB, [d][128 kv]
  __shared__ bf16 Pl[4 * 16 * 136];   // 17 KB, per-wave [16 q][128 kv] stride 136
  const int tid = threadIdx.x, lane = tid & 63, wid = tid >> 6;
  const int ql = lane & 15, lg = lane >> 4;
  const int flat = xcd_remap(blockIdx.y * 16 + blockIdx.x, 1024);
  const int bh = flat >> 4, b = bh >> 4, h = bh & 15;
  const int qrow0 = (flat & 15) * 64 + wid * 16;
  const size_t headq = (size_t)b * SEQ * 3072 + (size_t)h * 64;

  const bf16* qp = qkv + headq + (size_t)(qrow0 + ql) * 3072 + lg * 8;
  const bfrag q0 = *(const bfrag*)qp;
  const bfrag q1 = *(const bfrag*)(qp + 32);

  float mrun[4], lrun[4];
  ffrag oacc[4];
#pragma unroll
  for (int r = 0; r < 4; r++) { mrun[r] = -1e30f; lrun[r] = 0.0f; }
#pragma unroll
  for (int f = 0; f < 4; f++) oacc[f] = ffrag{0.f, 0.f, 0.f, 0.f};

  const int kr0 = tid >> 3;
  const int kjsw = ((tid & 7) ^ (kr0 & 7)) * 8;
  const bf16* kp = qkv + headq + 1024 + (size_t)kr0 * 3072 + kjsw;
  const int vr_ = tid >> 4, vlc = tid & 15;
  const bf16* vhead = vt + (size_t)bh * 64 * 1024;
  bf16* Pw = Pl + wid * 2176;

  for (int kt = 0; kt < SEQ; kt += 128) {
#pragma unroll
    for (int pp = 0; pp < 4; pp++)
      gload_lds16(kp + (size_t)(kt + pp * 32) * 3072, &Kl[pp * 2048 + tid * 8]);
#pragma unroll
    for (int pp = 0; pp < 4; pp++) {
      const int vr = pp * 16 + vr_;
      const int gc = vlc ^ (vr & 7);
      gload_lds16(vhead + (size_t)vr * 1024 + kt + gc * 8, &Vl[(pp * 256 + tid) * 8]);
    }
    __syncthreads();

    // QK^T: 8 subtiles of 16 keys
    ffrag sa[8];
    __builtin_amdgcn_s_setprio(1);
#pragma unroll
    for (int sub = 0; sub < 8; sub++) {
      const int krow = sub * 16 + ql;
      const int r7 = krow & 7;
      const bfrag kf0 = *(const bfrag*)&Kl[krow * 64 + ((lg ^ r7) * 8)];
      const bfrag kf1 = *(const bfrag*)&Kl[krow * 64 + (((lg + 4) ^ r7) * 8)];
      ffrag s4 = ffrag{0.f, 0.f, 0.f, 0.f};
      s4 = mfma16(q0, kf0, s4);
      s4 = mfma16(q1, kf1, s4);
      sa[sub] = s4;
    }
    __builtin_amdgcn_s_setprio(0);

    // lane-local row maxima
    float lmax[4];
#pragma unroll
    for (int r = 0; r < 4; r++) {
      float m = sa[0][r];
#pragma unroll
      for (int sub = 1; sub < 8; sub++) m = fmaxf(m, sa[sub][r]);
      lmax[r] = m;
    }
    // T13 defer-max: skip max-reduce + rescale unless some row grew > 8 (log2 units)
    bool ok = (lmax[0] - mrun[0] <= 8.0f) && (lmax[1] - mrun[1] <= 8.0f) &&
              (lmax[2] - mrun[2] <= 8.0f) && (lmax[3] - mrun[3] <= 8.0f);
    if (!__all(ok)) {
#pragma unroll
      for (int r = 0; r < 4; r++) {
        float mx = lmax[r];
        mx = fmaxf(mx, __shfl_xor(mx, 1));
        mx = fmaxf(mx, __shfl_xor(mx, 2));
        mx = fmaxf(mx, __shfl_xor(mx, 4));
        mx = fmaxf(mx, __shfl_xor(mx, 8));
        const float mnew = fmaxf(mrun[r], mx);
        const float corr = exp2f(mrun[r] - mnew);  // uniform across ql-group
        lrun[r] *= corr;
#pragma unroll
        for (int f = 0; f < 4; f++) oacc[f][r] *= corr;
        mrun[r] = mnew;
      }
    }
    // P = 2^(s - mrun); accumulate lane-local partial sums only
#pragma unroll
    for (int r = 0; r < 4; r++) {
      float srow = 0.f;
      bf16* prow = Pw + (lg * 4 + r) * 136;
#pragma unroll
      for (int sub = 0; sub < 8; sub++) {
        const float pv = exp2f(sa[sub][r] - mrun[r]);
        srow += pv;
        prow[sub * 16 + ql] = (bf16)pv;
      }
      lrun[r] += srow;
    }

    // PV: A = P (q=ql, kv chunk kc*32+lg*8), B = V^T rows d=f*16+ql from LDS
    bfrag pa[4];
#pragma unroll
    for (int kc = 0; kc < 4; kc++)
      pa[kc] = *(const bfrag*)&Pw[ql * 136 + kc * 32 + lg * 8];
    __builtin_amdgcn_s_setprio(1);
#pragma unroll
    for (int f = 0; f < 4; f++) {
      const int vrow = f * 16 + ql;
      const int r7 = vrow & 7;
#pragma unroll
      for (int kc = 0; kc < 4; kc++) {
        const bfrag vf = *(const bfrag*)&Vl[vrow * 128 + (((kc * 4 + lg) ^ r7) * 8)];
        oacc[f] = mfma16(pa[kc], vf, oacc[f]);
      }
    }
    __builtin_amdgcn_s_setprio(0);
    __syncthreads();
  }

  // epilogue: one row-sum reduce, then scale
  float rinv[4];
#pragma unroll
  for (int r = 0; r < 4; r++) {
    float ls = lrun[r];
    ls += __shfl_xor(ls, 1);
    ls += __shfl_xor(ls, 2);
    ls += __shfl_xor(ls, 4);
    ls += __shfl_xor(ls, 8);
    rinv[r] = 1.0f / ls;
  }
#pragma unroll
  for (int f = 0; f < 4; f++) {
#pragma unroll
    for (int r = 0; r < 4; r++) {
      const size_t orow = (size_t)b * SEQ + qrow0 + lg * 4 + r;
      o[orow * 1024 + h * 64 + f * 16 + ql] = (bf16)(oacc[f][r] * rinv[r]);
    }
  }
}

// ---------------------------------------------------------------- launch
extern "C" void kernel_launch(void* const* d_in, const int* in_sizes, int n_in,
                              void* d_out, int out_size, void* d_ws, size_t ws_size,
                              hipStream_t stream) {
  (void)in_sizes; (void)n_in; (void)out_size; (void)ws_size;
  const float* x      = (const float*)d_in[0];
  const float* in_w   = (const float*)d_in[1];
  const float* in_b   = (const float*)d_in[2];
  const float* out_w  = (const float*)d_in[3];
  const float* out_b  = (const float*)d_in[4];
  const float* ln1_g  = (const float*)d_in[5];
  const float* ln1_b  = (const float*)d_in[6];
  const float* fc_w   = (const float*)d_in[7];
  const float* fc_b   = (const float*)d_in[8];
  const float* proj_w = (const float*)d_in[9];
  const float* proj_b = (const float*)d_in[10];
  const float* ln2_g  = (const float*)d_in[11];
  const float* ln2_b  = (const float*)d_in[12];
  float* out = (float*)d_out;

  char* p = (char*)d_ws;
  auto alloc = [&](size_t bytes) { char* r = p; p += (bytes + 255) & ~255ull; return r; };
  bf16* w_qkv  = (bf16*)alloc((size_t)3072 * 1024 * 2);
  bf16* w_out  = (bf16*)alloc((size_t)1024 * 1024 * 2);
  bf16* w_fc   = (bf16*)alloc((size_t)4096 * 1024 * 2);
  bf16* w_proj = (bf16*)alloc((size_t)1024 * 4096 * 2);
  float* b_qkv = (float*)alloc((size_t)3072 * 4);
  bf16* hbuf   = (bf16*)alloc((size_t)NTOK * 1024 * 2);   // LN1 out; reused as LN2 out
  float* x2    = (float*)alloc((size_t)NTOK * 1024 * 4);
  bf16* qkv    = (bf16*)alloc((size_t)NTOK * 3072 * 2);
  bf16* aout   = (bf16*)alloc((size_t)NTOK * 1024 * 2);
  bf16* ubuf   = qkv;              // aliases qkv+aout (both dead by GEMM3)
  bf16* vtb    = (bf16*)x2;        // VT [64 bh][64 d][1024 s] = 8MB; x2 written only after flash

  // fold head-scaling AND log2(e) (log2-domain softmax) into q weights+bias
  const float scaling = 0.125f * 1.44269504089f;
  convert_all<<<dim3(1024, 4), 256, 0, stream>>>(
      in_w, w_qkv, 3072 * 1024 / 4,
      out_w, w_out, 1024 * 1024 / 4,
      fc_w, w_fc, 4096 * 1024 / 4,
      proj_w, w_proj, 4096 * 1024 / 4,
      scaling, 1024 * 1024 / 4);
  scale_bias<<<12, 256, 0, stream>>>(in_b, b_qkv, 3072, 1024, scaling);

  ln_row<<<NTOK, 256, 0, stream>>>(x, ln1_g, ln1_b, hbuf);
  gemm_bt<0><<<dim3(32, 24), 256, 0, stream>>>(hbuf, w_qkv, b_qkv, nullptr,
                                               nullptr, qkv, NTOK, 3072, 1024);
  transpose_v<<<dim3(16, 64), 256, 0, stream>>>(qkv, vtb);
  flash_attn<<<dim3(16, 64), 256, 0, stream>>>(qkv, vtb, aout);
  gemm_bt64<1><<<dim3(64, 16), 256, 0, stream>>>(aout, w_out, out_b, x,
                                                 x2, nullptr, NTOK, 1024, 1024);
  ln_row<<<NTOK, 256, 0, stream>>>(x2, ln2_g, ln2_b, hbuf);
  gemm_bt<2><<<dim3(32, 32), 256, 0, stream>>>(hbuf, w_fc, fc_b, nullptr,
                                               nullptr, ubuf, NTOK, 4096, 1024);
  gemm_bt64<1><<<dim3(64, 16), 256, 0, stream>>>(ubuf, w_proj, proj_b, x2,
                                                 out, nullptr, NTOK, 1024, 4096);
}